// Round 1
// baseline (1210.537 us; speedup 1.0000x reference)
//
#include <hip/hip_runtime.h>
#include <hip/hip_bf16.h>

#define IGNORE_INDEX (-100)

typedef __attribute__((ext_vector_type(8))) unsigned short u16x8;

__device__ __forceinline__ float bf16_bits_to_f32(unsigned short u) {
    union { unsigned int i; float f; } cvt;
    cvt.i = ((unsigned int)u) << 16;
    return cvt.f;
}

// One block per token row. Online logsumexp over V elements, then compute
// loss*ratio for this token and a validity flag, written to ws[t] / ws[rows+t].
__global__ __launch_bounds__(256) void ce_row_kernel(
    const __hip_bfloat16* __restrict__ logits,
    const float* __restrict__ ref_logprobs,
    const int* __restrict__ labels,
    float* __restrict__ ws,
    int rows, int V)
{
    const int t = blockIdx.x;
    const unsigned short* row = (const unsigned short*)(logits) + (size_t)t * V;
    const u16x8* row8 = (const u16x8*)row;
    const int V8 = V >> 3;   // V divisible by 8 (128256 = 8*16032)

    float m = -INFINITY;
    float s = 0.0f;

    for (int i = threadIdx.x; i < V8; i += 256) {
        u16x8 u = row8[i];
        float x0 = bf16_bits_to_f32(u[0]);
        float x1 = bf16_bits_to_f32(u[1]);
        float x2 = bf16_bits_to_f32(u[2]);
        float x3 = bf16_bits_to_f32(u[3]);
        float x4 = bf16_bits_to_f32(u[4]);
        float x5 = bf16_bits_to_f32(u[5]);
        float x6 = bf16_bits_to_f32(u[6]);
        float x7 = bf16_bits_to_f32(u[7]);
        float cmax = fmaxf(fmaxf(fmaxf(x0, x1), fmaxf(x2, x3)),
                           fmaxf(fmaxf(x4, x5), fmaxf(x6, x7)));
        float nm = fmaxf(m, cmax);
        // branchless rescale of running sum (exp(m-nm)=1 when no new max;
        // first iteration: m=-inf -> exp(-inf)=0, s stays 0)
        s *= __expf(m - nm);
        float e01 = __expf(x0 - nm) + __expf(x1 - nm);
        float e23 = __expf(x2 - nm) + __expf(x3 - nm);
        float e45 = __expf(x4 - nm) + __expf(x5 - nm);
        float e67 = __expf(x6 - nm) + __expf(x7 - nm);
        s += (e01 + e23) + (e45 + e67);
        m = nm;
    }

    // wave-level (m,s) combine over 64 lanes
    #pragma unroll
    for (int off = 32; off; off >>= 1) {
        float om = __shfl_xor(m, off);
        float os = __shfl_xor(s, off);
        float nm = fmaxf(m, om);
        s = s * __expf(m - nm) + os * __expf(om - nm);
        m = nm;
    }

    __shared__ float sm[4];
    __shared__ float ss[4];
    const int wave = threadIdx.x >> 6;
    const int lane = threadIdx.x & 63;
    if (lane == 0) { sm[wave] = m; ss[wave] = s; }
    __syncthreads();

    if (threadIdx.x == 0) {
        float M = sm[0], S = ss[0];
        #pragma unroll
        for (int w = 1; w < 4; w++) {
            float nm = fmaxf(M, sm[w]);
            S = S * __expf(M - nm) + ss[w] * __expf(sm[w] - nm);
            M = nm;
        }
        float lse = M + __logf(S);

        int lbl = labels[t];
        float loss_ratio = 0.0f;
        float valid = 0.0f;
        if (lbl != IGNORE_INDEX) {
            int idx = lbl < 0 ? 0 : (lbl > V - 1 ? V - 1 : lbl);
            float lg = bf16_bits_to_f32(row[idx]);   // row is hot in cache
            float sel = lg - lse;                     // log-prob of label token
            float ratio = __expf(sel - ref_logprobs[t]);
            loss_ratio = (-sel) * ratio;              // loss * ratio
            valid = 1.0f;
        }
        ws[t] = loss_ratio;
        ws[rows + t] = valid;
    }
}

// Single-block final reduction: out = sum(loss*ratio) / sum(valid)
__global__ __launch_bounds__(256) void ce_finalize_kernel(
    const float* __restrict__ ws, float* __restrict__ out, int rows)
{
    float a = 0.0f, b = 0.0f;
    for (int i = threadIdx.x; i < rows; i += 256) {
        a += ws[i];
        b += ws[rows + i];
    }
    #pragma unroll
    for (int off = 32; off; off >>= 1) {
        a += __shfl_xor(a, off);
        b += __shfl_xor(b, off);
    }
    __shared__ float sa[4];
    __shared__ float sb[4];
    const int wave = threadIdx.x >> 6;
    const int lane = threadIdx.x & 63;
    if (lane == 0) { sa[wave] = a; sb[wave] = b; }
    __syncthreads();
    if (threadIdx.x == 0) {
        float A = sa[0] + sa[1] + sa[2] + sa[3];
        float B = sb[0] + sb[1] + sb[2] + sb[3];
        out[0] = A / B;
    }
}

extern "C" void kernel_launch(void* const* d_in, const int* in_sizes, int n_in,
                              void* d_out, int out_size, void* d_ws, size_t ws_size,
                              hipStream_t stream) {
    const __hip_bfloat16* logits = (const __hip_bfloat16*)d_in[0];
    const float* ref_logprobs    = (const float*)d_in[1];
    const int* labels            = (const int*)d_in[2];
    float* out = (float*)d_out;
    float* ws  = (float*)d_ws;

    const int rows = in_sizes[1];              // B*T = 2048
    const int V    = in_sizes[0] / rows;       // 128256

    ce_row_kernel<<<rows, 256, 0, stream>>>(logits, ref_logprobs, labels, ws, rows, V);
    ce_finalize_kernel<<<1, 256, 0, stream>>>(ws, out, rows);
}

// Round 8
// 1158.735 us; speedup vs baseline: 1.0447x; 1.0447x over previous
//
#include <hip/hip_runtime.h>
#include <hip/hip_bf16.h>

#define IGNORE_INDEX (-100)

typedef __attribute__((ext_vector_type(8))) unsigned short u16x8;

__device__ __forceinline__ float bf16_bits_to_f32(unsigned short u) {
    union { unsigned int i; float f; } cvt;
    cvt.i = ((unsigned int)u) << 16;
    return cvt.f;
}

// Online-logsumexp update for 8 bf16 values against running (m, s).
__device__ __forceinline__ void online8(u16x8 u, float& m, float& s) {
    float x0 = bf16_bits_to_f32(u[0]);
    float x1 = bf16_bits_to_f32(u[1]);
    float x2 = bf16_bits_to_f32(u[2]);
    float x3 = bf16_bits_to_f32(u[3]);
    float x4 = bf16_bits_to_f32(u[4]);
    float x5 = bf16_bits_to_f32(u[5]);
    float x6 = bf16_bits_to_f32(u[6]);
    float x7 = bf16_bits_to_f32(u[7]);
    float cmax = fmaxf(fmaxf(fmaxf(x0, x1), fmaxf(x2, x3)),
                       fmaxf(fmaxf(x4, x5), fmaxf(x6, x7)));
    float nm = fmaxf(m, cmax);
    // branchless rescale (exp(0)=1 when no new max; m=-inf first iter -> 0)
    s *= __expf(m - nm);
    float e01 = __expf(x0 - nm) + __expf(x1 - nm);
    float e23 = __expf(x2 - nm) + __expf(x3 - nm);
    float e45 = __expf(x4 - nm) + __expf(x5 - nm);
    float e67 = __expf(x6 - nm) + __expf(x7 - nm);
    s += (e01 + e23) + (e45 + e67);
    m = nm;
}

// One block (4 waves) per token row. Two independent (m,s) chains per lane
// (row split in halves -> 2x ILP on the serial exp chain, both streams
// dense-coalesced). Nontemporal loads: logits are streamed read-once.
__global__ __launch_bounds__(256) void ce_row_kernel(
    const __hip_bfloat16* __restrict__ logits,
    const float* __restrict__ ref_logprobs,
    const int* __restrict__ labels,
    float* __restrict__ ws,
    int rows, int V)
{
    const int t = blockIdx.x;
    const unsigned short* row = (const unsigned short*)(logits) + (size_t)t * V;
    const u16x8* row8 = (const u16x8*)row;
    const int half8 = V >> 4;   // V divisible by 16 (128256 = 16*8016)

    float m0 = -INFINITY, s0 = 0.0f;
    float m1 = -INFINITY, s1 = 0.0f;

    for (int i = threadIdx.x; i < half8; i += 256) {
        u16x8 a = __builtin_nontemporal_load(&row8[i]);
        u16x8 b = __builtin_nontemporal_load(&row8[half8 + i]);
        online8(a, m0, s0);
        online8(b, m1, s1);
    }

    // merge the two chains
    float m = fmaxf(m0, m1);
    float s = s0 * __expf(m0 - m) + s1 * __expf(m1 - m);

    // wave-level (m,s) combine over 64 lanes
    #pragma unroll
    for (int off = 32; off; off >>= 1) {
        float om = __shfl_xor(m, off);
        float os = __shfl_xor(s, off);
        float nm = fmaxf(m, om);
        s = s * __expf(m - nm) + os * __expf(om - nm);
        m = nm;
    }

    __shared__ float sm[4];
    __shared__ float ss[4];
    const int wave = threadIdx.x >> 6;
    const int lane = threadIdx.x & 63;
    if (lane == 0) { sm[wave] = m; ss[wave] = s; }
    __syncthreads();

    if (threadIdx.x == 0) {
        float M = sm[0], S = ss[0];
        #pragma unroll
        for (int w = 1; w < 4; w++) {
            float nm = fmaxf(M, sm[w]);
            S = S * __expf(M - nm) + ss[w] * __expf(sm[w] - nm);
            M = nm;
        }
        float lse = M + __logf(S);

        int lbl = labels[t];
        float loss_ratio = 0.0f;
        float valid = 0.0f;
        if (lbl != IGNORE_INDEX) {
            int idx = lbl < 0 ? 0 : (lbl > V - 1 ? V - 1 : lbl);
            float lg = bf16_bits_to_f32(row[idx]);   // label gather (1 elem)
            float sel = lg - lse;                     // log-prob of label token
            float ratio = __expf(sel - ref_logprobs[t]);
            loss_ratio = (-sel) * ratio;              // loss * ratio
            valid = 1.0f;
        }
        ws[t] = loss_ratio;
        ws[rows + t] = valid;
    }
}

// Single-block final reduction: out = sum(loss*ratio) / sum(valid)
__global__ __launch_bounds__(256) void ce_finalize_kernel(
    const float* __restrict__ ws, float* __restrict__ out, int rows)
{
    float a = 0.0f, b = 0.0f;
    for (int i = threadIdx.x; i < rows; i += 256) {
        a += ws[i];
        b += ws[rows + i];
    }
    #pragma unroll
    for (int off = 32; off; off >>= 1) {
        a += __shfl_xor(a, off);
        b += __shfl_xor(b, off);
    }
    __shared__ float sa[4];
    __shared__ float sb[4];
    const int wave = threadIdx.x >> 6;
    const int lane = threadIdx.x & 63;
    if (lane == 0) { sa[wave] = a; sb[wave] = b; }
    __syncthreads();
    if (threadIdx.x == 0) {
        float A = sa[0] + sa[1] + sa[2] + sa[3];
        float B = sb[0] + sb[1] + sb[2] + sb[3];
        out[0] = A / B;
    }
}

extern "C" void kernel_launch(void* const* d_in, const int* in_sizes, int n_in,
                              void* d_out, int out_size, void* d_ws, size_t ws_size,
                              hipStream_t stream) {
    const __hip_bfloat16* logits = (const __hip_bfloat16*)d_in[0];
    const float* ref_logprobs    = (const float*)d_in[1];
    const int* labels            = (const int*)d_in[2];
    float* out = (float*)d_out;
    float* ws  = (float*)d_ws;

    const int rows = in_sizes[1];              // B*T = 2048
    const int V    = in_sizes[0] / rows;       // 128256

    ce_row_kernel<<<rows, 256, 0, stream>>>(logits, ref_logprobs, labels, ws, rows, V);
    ce_finalize_kernel<<<1, 256, 0, stream>>>(ws, out, rows);
}